// Round 1
// baseline (97.293 us; speedup 1.0000x reference)
//
#include <hip/hip_runtime.h>

// FineMatching fused v6: 256 blocks x 512 threads, TWO proposals per block,
// software-pipelined with async global->LDS DMA (global_load_lds, width=16).
// - LDS: 2 x 64KB tiles (ping-pong) + thirds[2][128]  = 129 KB  -> 1 block/CU.
// - DMA writes LDS linearly; XOR swizzle (slot = c4 ^ (row&31)) is applied to
//   the GLOBAL source address instead (involution => read side identical to v5).
// - Pipeline: issue DMA(p1) -> scans(p0) -> barrier (implicit vmcnt(0) doubles
//   as DMA-complete wait) -> epilogue(p0) stores overlap scans(p1).
// - Row scan keeps x[8] in registers: epilogue stays register-resident.
// d_out = [score_map (P*R*S), corr_map (P*R*S)] f32.

typedef float vf4 __attribute__((ext_vector_type(4)));
typedef int   vi4 __attribute__((ext_vector_type(4)));

constexpr int NP = 512;
constexpr int NR = 128;
constexpr int NS = 128;
constexpr int RS = NR * NS;          // 16384 floats = 64 KB
constexpr float THRESHOLD = 0.05f;
constexpr float NEG_INF = -3.4e38f;

__device__ __forceinline__ void top3_insert(float v, float& m0, float& m1, float& m2) {
    // 3 VALU: v_max + 2x v_med3 (sorted m0>=m1>=m2 invariant)
    float n1 = __builtin_amdgcn_fmed3f(v, m0, m1);
    float n2 = __builtin_amdgcn_fmed3f(v, m1, m2);
    m0 = fmaxf(m0, v);
    m1 = n1; m2 = n2;
}

__device__ __forceinline__ void shfl_merge3(int d, float& m0, float& m1, float& m2) {
    float o0 = __shfl_xor(m0, d);
    float o1 = __shfl_xor(m1, d);
    float o2 = __shfl_xor(m2, d);
    top3_insert(o0, m0, m1, m2);
    top3_insert(o1, m0, m1, m2);
    top3_insert(o2, m0, m1, m2);
}

// Async global->LDS DMA, 16 B/lane. LDS dest is wave-uniform base + lane*16;
// global src is per-lane (pre-swizzled).
__device__ __forceinline__ void async_load16(const float* g, float* l) {
    __builtin_amdgcn_global_load_lds(
        (__attribute__((address_space(1))) void*)(g),
        (__attribute__((address_space(3))) void*)(l), 16, 0, 0);
}

__global__ __launch_bounds__(512, 2) void fused_kernel(
    const float* __restrict__ in,     // [P,R,S] raw log-scores
    const int*   __restrict__ rmask,  // [P,R]
    const int*   __restrict__ smask,  // [P,S]
    const float* __restrict__ ncs,    // [P]
    float*       __restrict__ out)    // [2,P,R,S]
{
    __shared__ vf4 tile4[2][RS / 4];              // 128 KB, XOR-swizzled layout
    __shared__ __align__(16) float thirds[2][NS]; // 1 KB, per-proposal col thirds

    const int t    = threadIdx.x;
    const int wv   = t >> 6;          // wave 0..7
    const int lane = t & 63;
    const int row  = t >> 2;          // this thread's row (scan + epilogue)
    const int q    = t & 3;           // quarter within row
    const int p0   = blockIdx.x * 2;

    const float* src0 = in + (size_t)p0 * RS;
    const float* src1 = in + (size_t)(p0 + 1) * RS;

    // ---- Prologue: DMA proposal p0 into tile 0.
    // LDS slot (r, s) holds column c4 = s ^ (r&31)  (same layout as v5).
    // DMA j of wave wv fills linear vf4 slots [(wv*8+j)*64, +64); lane l's
    // 16 B land at slot +l, so the global source is the inverse-swizzled addr.
    #pragma unroll
    for (int j = 0; j < 8; ++j) {
        int s  = (wv * 8 + j) * 64 + lane;
        int r  = s >> 5;
        int c4 = (s & 31) ^ (r & 31);
        async_load16(src0 + r * 128 + c4 * 4, (float*)&tile4[0][(wv * 8 + j) * 64]);
    }
    const float halfnc0 = 0.5f * ncs[p0];
    const float halfnc1 = 0.5f * ncs[p0 + 1];
    const float mrf0 = (rmask[p0 * NR + row] != 0) ? 1.0f : 0.0f;
    const float mrf1 = (rmask[(p0 + 1) * NR + row] != 0) ? 1.0f : 0.0f;
    __syncthreads();                  // implicit vmcnt(0) drain: tile0 ready

    #pragma unroll
    for (int pp = 0; pp < 2; ++pp) {
        const int p = p0 + pp;

        if (pp == 0) {
            // Pipeline: issue DMA for p0+1 into tile1 now; HBM latency hides
            // under the scans below; completion guaranteed by this
            // iteration's __syncthreads (pre-barrier vmcnt(0) drain).
            #pragma unroll
            for (int j = 0; j < 8; ++j) {
                int s  = (wv * 8 + j) * 64 + lane;
                int r  = s >> 5;
                int c4 = (s & 31) ^ (r & 31);
                async_load16(src1 + r * 128 + c4 * 4,
                             (float*)&tile4[1][(wv * 8 + j) * 64]);
            }
        }

        // smask quarters for the epilogue (512 B/block, L2-hit; hide under scans)
        const vi4* sm4 = (const vi4*)(smask + (size_t)p * NS);
        vi4 ms[8];
        #pragma unroll
        for (int j = 0; j < 8; ++j) ms[j] = sm4[q + 4 * j];

        // ---- Row scan from swizzled tile; keep x[8] for the epilogue.
        const vf4* tb = tile4[pp];
        vf4 x[8];
        float r0 = NEG_INF, r1 = NEG_INF, r2 = NEG_INF;
        #pragma unroll
        for (int j = 0; j < 8; ++j) {
            int c4 = q + 4 * j;
            x[j] = tb[row * 32 + (c4 ^ (row & 31))];
            top3_insert(x[j].x, r0, r1, r2);
            top3_insert(x[j].y, r0, r1, r2);
            top3_insert(x[j].z, r0, r1, r2);
            top3_insert(x[j].w, r0, r1, r2);
        }
        shfl_merge3(1, r0, r1, r2);   // merge quarter-group (lanes 4r..4r+3)
        shfl_merge3(2, r0, r1, r2);
        const float tr = r2;          // row third

        // ---- Col scan (transposed access via XOR swizzle; ~2-way aliasing).
        {
            const int col = t >> 2, seg = t & 3;
            const int c4c = col >> 2, cw = col & 3;
            const float* tf = (const float*)tb;
            float c0 = NEG_INF, c1 = NEG_INF, c2 = NEG_INF;
            #pragma unroll 8
            for (int i = 0; i < 32; ++i) {
                int r = 4 * seg + (i & 3) + 16 * (i >> 2);
                top3_insert(tf[r * 128 + ((c4c ^ (r & 31)) << 2) + cw], c0, c1, c2);
            }
            shfl_merge3(1, c0, c1, c2);   // merge segs (lanes 4c..4c+3)
            shfl_merge3(2, c0, c1, c2);
            if (seg == 0) thirds[pp][col] = c2;
        }
        __syncthreads();              // thirds[pp] ready; DMA tile1 drained

        // ---- Epilogue from registers; tc from LDS (broadcast); coalesced
        //      float4 stores. These stores overlap the NEXT proposal's scans
        //      (no barrier between epilogue and the pp=1 scan phase).
        const float halfnc = pp ? halfnc1 : halfnc0;
        const float mrf    = pp ? mrf1 : mrf0;
        vf4* sc4 = (vf4*)(out + (size_t)p * RS);
        vf4* co4 = (vf4*)(out + (size_t)(NP + p) * RS);
        const vf4* th4 = (const vf4*)thirds[pp];

        #pragma unroll
        for (int j = 0; j < 8; ++j) {
            int c4 = q + 4 * j;
            vf4 tc = th4[c4];
            vi4 m  = ms[j];
            vf4 v  = x[j];
            vf4 sc, co;

            {   float e = __expf(v.x);
                float w2 = ((v.x >= tr) ? halfnc : 0.f) + ((v.x >= tc.x) ? halfnc : 0.f);
                sc.x = e * w2;
                float mk = (m.x != 0) ? mrf : 0.f;
                co.x = (e > THRESHOLD && w2 > 0.f) ? mk : 0.f; }
            {   float e = __expf(v.y);
                float w2 = ((v.y >= tr) ? halfnc : 0.f) + ((v.y >= tc.y) ? halfnc : 0.f);
                sc.y = e * w2;
                float mk = (m.y != 0) ? mrf : 0.f;
                co.y = (e > THRESHOLD && w2 > 0.f) ? mk : 0.f; }
            {   float e = __expf(v.z);
                float w2 = ((v.z >= tr) ? halfnc : 0.f) + ((v.z >= tc.z) ? halfnc : 0.f);
                sc.z = e * w2;
                float mk = (m.z != 0) ? mrf : 0.f;
                co.z = (e > THRESHOLD && w2 > 0.f) ? mk : 0.f; }
            {   float e = __expf(v.w);
                float w2 = ((v.w >= tr) ? halfnc : 0.f) + ((v.w >= tc.w) ? halfnc : 0.f);
                sc.w = e * w2;
                float mk = (m.w != 0) ? mrf : 0.f;
                co.w = (e > THRESHOLD && w2 > 0.f) ? mk : 0.f; }

            sc4[row * 32 + c4] = sc;
            co4[row * 32 + c4] = co;
        }
    }
}

extern "C" void kernel_launch(void* const* d_in, const int* in_sizes, int n_in,
                              void* d_out, int out_size, void* d_ws, size_t ws_size,
                              hipStream_t stream) {
    const float* msm   = (const float*)d_in[0];  // [P,R,S] f32
    const int*   rmask = (const int*)  d_in[1];  // [P,R]
    const int*   smask = (const int*)  d_in[2];  // [P,S]
    const float* ncs   = (const float*)d_in[3];  // [P]
    float* out = (float*)d_out;

    fused_kernel<<<NP / 2, 512, 0, stream>>>(msm, rmask, smask, ncs, out);
}